// Round 15
// baseline (120.970 us; speedup 1.0000x reference)
//
#include <hip/hip_runtime.h>

typedef __bf16 bf16;
typedef __attribute__((ext_vector_type(8))) __bf16 bf16x8;
typedef __attribute__((ext_vector_type(4))) float f32x4;
typedef __attribute__((ext_vector_type(16))) float f32x16;
typedef __attribute__((ext_vector_type(4))) unsigned u32x4;

#define MFMA16(a, b, c) __builtin_amdgcn_mfma_f32_16x16x32_bf16((a), (b), (c), 0, 0, 0)
#define MFMA32(a, b, c) __builtin_amdgcn_mfma_f32_32x32x16_bf16((a), (b), (c), 0, 0, 0)
#define NEG_BIG (-1e30f)
#define SCL_LOG2 0.18033688011112042f  /* log2(e)/sqrt(64) */
#define THR_RAW 44.3614195558365f      /* 8 / SCL_LOG2 */

__device__ __forceinline__ void gload_lds16(void* lds, const void* g) {
  __builtin_amdgcn_global_load_lds(
      (const __attribute__((address_space(1))) void*)g,
      (__attribute__((address_space(3))) void*)lds, 16, 0, 0);
}

__device__ __forceinline__ unsigned pk2(float x, float y) {
  const unsigned short a = __builtin_bit_cast(unsigned short, (bf16)x);
  const unsigned short b = __builtin_bit_cast(unsigned short, (bf16)y);
  return (unsigned)a | ((unsigned)b << 16);
}

// Round-10 LPT schedule (measured best): kind -> (qt, seg).
// ns(qt): qt>=11 -> 3, 5..10 -> 2, else 1. Max chain = 11 tiles.
static __device__ const signed char KQT[32] =
  {15,15,10,10, 15,14,14,14,13, 9, 9, 4, 13,13,12,12, 8, 8,
   12,11,11,11, 7, 7, 3,  6, 6,  5, 5, 2,  1,  0};
static __device__ const signed char KSEG[32] =
  { 0, 1, 0, 1,  2, 0, 1, 2, 0, 0, 1, 0,  1, 2, 0, 1, 0, 1,
    2, 0, 1, 2, 0, 1, 0,  0, 1,  0, 1, 0,  0,  0};

// ---------------------------------------------------------------------------
// Fused f32 -> bf16 conversion for all 6 tensors (1 launch).
// ---------------------------------------------------------------------------
__global__ void cvt6(const float* __restrict__ s0, const float* __restrict__ s1,
                     const float* __restrict__ s2, const float* __restrict__ s3,
                     const float* __restrict__ s4, const float* __restrict__ s5,
                     bf16* __restrict__ d0, bf16* __restrict__ d1,
                     bf16* __restrict__ d2, bf16* __restrict__ d3,
                     bf16* __restrict__ d4, bf16* __restrict__ d5) {
  const int c = blockIdx.x * blockDim.x + threadIdx.x;
  if (c >= 1572864) return;
  const float* s; bf16* d; int off;
  if (c < 524288)        { s = s0; d = d0; off = c; }
  else if (c < 1048576)  { s = s1; d = d1; off = c - 524288; }
  else {
    const int c2 = c - 1048576, seg = c2 >> 17;
    off = c2 & 131071;
    s = seg == 0 ? s2 : seg == 1 ? s3 : seg == 2 ? s4 : s5;
    d = seg == 0 ? d2 : seg == 1 ? d3 : seg == 2 ? d4 : d5;
  }
  const float4 a = ((const float4*)s)[off * 2 + 0];
  const float4 b = ((const float4*)s)[off * 2 + 1];
  bf16x8 o;
  o[0] = (bf16)a.x; o[1] = (bf16)a.y; o[2] = (bf16)a.z; o[3] = (bf16)a.w;
  o[4] = (bf16)b.x; o[5] = (bf16)b.y; o[6] = (bf16)b.z; o[7] = (bf16)b.w;
  ((bf16x8*)d)[off] = o;
}

// ---------------------------------------------------------------------------
// Merged Q+K+V projection, BK=64 (round-12 verified): 768 blocks (3/CU).
// ---------------------------------------------------------------------------
__global__ void gemm_qkv(const bf16* __restrict__ XQ, const bf16* __restrict__ X,
                         const bf16* __restrict__ Wq, const bf16* __restrict__ Wk,
                         const bf16* __restrict__ Wv,
                         const float* __restrict__ bq, const float* __restrict__ bk,
                         const float* __restrict__ bv,
                         bf16* __restrict__ Qo, bf16* __restrict__ Ko,
                         bf16* __restrict__ Vto) {
  __shared__ __align__(16) char As[128 * 128];   // [row][64 elems swz]
  __shared__ __align__(16) char Bs[128 * 128];
  const int tid = threadIdx.x;
  const int wv = tid >> 6, lane = tid & 63;
  const int wr = wv >> 1, wc = wv & 1;
  const int lr = lane & 15, lg = lane >> 4;
  const int seg = blockIdx.x >> 3;
  const int n0 = (blockIdx.x & 7) * 128;
  const int m0 = blockIdx.y * 128;
  const bf16* __restrict__ A = seg == 0 ? XQ : X;
  const bf16* __restrict__ W = seg == 0 ? Wq : seg == 1 ? Wk : Wv;
  const float* __restrict__ bias = seg == 0 ? bq : seg == 1 ? bk : bv;
  const int K = 1024;

  f32x4 acc[4][4] = {};

  for (int k0 = 0; k0 < K; k0 += 64) {
    __syncthreads();
#pragma unroll
    for (int j = 0; j < 4; ++j) {
      const int c = j * 256 + tid;
      const int row = c >> 3, cc = c & 7;
      const int gcol = (cc ^ (row & 7)) * 8;
      gload_lds16(As + (j * 256 + wv * 64) * 16,
                  A + (size_t)(m0 + row) * K + k0 + gcol);
      gload_lds16(Bs + (j * 256 + wv * 64) * 16,
                  W + (size_t)(n0 + row) * K + k0 + gcol);
    }
    __syncthreads();
#pragma unroll
    for (int half = 0; half < 2; ++half) {
      const int kb = half * 64 + lg * 16;
      bf16x8 af[4], bfr[4];
#pragma unroll
      for (int i = 0; i < 4; ++i) {
        const int row = wr * 64 + i * 16 + lr;
        af[i] = *(const bf16x8*)(As + row * 128 + (kb ^ ((row & 7) << 4)));
      }
#pragma unroll
      for (int j = 0; j < 4; ++j) {
        const int row = wc * 64 + j * 16 + lr;
        bfr[j] = *(const bf16x8*)(Bs + row * 128 + (kb ^ ((row & 7) << 4)));
      }
#pragma unroll
      for (int i = 0; i < 4; ++i)
#pragma unroll
        for (int j = 0; j < 4; ++j)
          acc[i][j] = MFMA16(af[i], bfr[j], acc[i][j]);
    }
  }

#pragma unroll
  for (int j = 0; j < 4; ++j) {
    const int n = n0 + wc * 64 + j * 16 + lr;
    const float bvv = bias[n];
    const int h = n >> 6, d = n & 63;
#pragma unroll
    for (int i = 0; i < 4; ++i) {
#pragma unroll
      for (int r = 0; r < 4; ++r) {
        const int m = m0 + wr * 64 + i * 16 + lg * 4 + r;
        const float v = acc[i][j][r] + bvv;
        const int b = m >> 11, t = m & 2047;
        if (seg == 0)      Qo[((size_t)(b * 16 + h) * 2048 + t) * 64 + d] = (bf16)v;
        else if (seg == 1) Ko[((size_t)(b * 16 + h) * 2048 + t) * 64 + d] = (bf16)v;
        else               Vto[((size_t)(b * 16 + h) * 64 + d) * 2048 + t] = (bf16)v;
      }
    }
  }
}

// ---------------------------------------------------------------------------
// Final projection GEMM, BK=64, BN=64 (round-12 verified): 512 blocks.
// ---------------------------------------------------------------------------
__global__ void gemm_out(const bf16* __restrict__ A, const bf16* __restrict__ W,
                         const float* __restrict__ bias, float* __restrict__ out,
                         int M, int N, int K) {
  __shared__ __align__(16) char As[128 * 128];  // [row][64 elems swz]
  __shared__ __align__(16) char Bs[64 * 128];
  const int tid = threadIdx.x;
  const int wv = tid >> 6, lane = tid & 63;
  const int wr = wv >> 1, wc = wv & 1;
  const int lr = lane & 15, lg = lane >> 4;
  const int m0 = blockIdx.y * 128, n0 = blockIdx.x * 64;

  f32x4 acc[4][2] = {};

  for (int k0 = 0; k0 < K; k0 += 64) {
    __syncthreads();
#pragma unroll
    for (int j = 0; j < 4; ++j) {
      const int c = j * 256 + tid;
      const int row = c >> 3, cc = c & 7;
      const int gcol = (cc ^ (row & 7)) * 8;
      gload_lds16(As + (j * 256 + wv * 64) * 16,
                  A + (size_t)(m0 + row) * K + k0 + gcol);
    }
#pragma unroll
    for (int j = 0; j < 2; ++j) {
      const int c = j * 256 + tid;
      const int row = c >> 3, cc = c & 7;
      const int gcol = (cc ^ (row & 7)) * 8;
      gload_lds16(Bs + (j * 256 + wv * 64) * 16,
                  W + (size_t)(n0 + row) * K + k0 + gcol);
    }
    __syncthreads();
#pragma unroll
    for (int half = 0; half < 2; ++half) {
      const int kb = half * 64 + lg * 16;
      bf16x8 af[4], bfr[2];
#pragma unroll
      for (int i = 0; i < 4; ++i) {
        const int row = wr * 64 + i * 16 + lr;
        af[i] = *(const bf16x8*)(As + row * 128 + (kb ^ ((row & 7) << 4)));
      }
#pragma unroll
      for (int j = 0; j < 2; ++j) {
        const int row = wc * 32 + j * 16 + lr;
        bfr[j] = *(const bf16x8*)(Bs + row * 128 + (kb ^ ((row & 7) << 4)));
      }
#pragma unroll
      for (int i = 0; i < 4; ++i)
#pragma unroll
        for (int j = 0; j < 2; ++j)
          acc[i][j] = MFMA16(af[i], bfr[j], acc[i][j]);
    }
  }

#pragma unroll
  for (int j = 0; j < 2; ++j) {
    const int n = n0 + wc * 32 + j * 16 + lr;
    const float bv = bias[n];
#pragma unroll
    for (int i = 0; i < 4; ++i) {
#pragma unroll
      for (int r = 0; r < 4; ++r) {
        const int m = m0 + wr * 64 + i * 16 + lg * 4 + r;
        out[(size_t)m * N + n] = acc[i][j][r] + bv;
      }
    }
  }
}

// ---------------------------------------------------------------------------
// Causal flash attention — round 15: K x3 / V x2 buffers, counted vmcnt.
// Same grid/tables/math as round 10/14. LDS = 24+16 = 40KB -> 4 blocks/CU
// (unchanged). Per iter t: issue STAGE_V(t+1) THEN STAGE_K(t+2); boundary
// wait = s_waitcnt vmcnt(2) (leaves only K(t+2)'s 2 loads in flight; FIFO
// oldest-first semantics guarantee V(t+1) and K(t+1) landed) + raw s_barrier.
// Never vmcnt(0) in steady state. Hazards: every buffer overwrite is >=2
// iters after its last read; all waves issue identical STAGEs.
// ---------------------------------------------------------------------------
__global__ void attn_fwd(const bf16* __restrict__ Q, const bf16* __restrict__ Kk,
                         const bf16* __restrict__ Vt, bf16* __restrict__ attout,
                         bf16* __restrict__ Opart, float* __restrict__ Ml) {
  __shared__ __align__(16) char Ks[3][8192];   // [kv 64][d swz 128B]
  __shared__ __align__(16) char Vs[2][8192];   // [d 64][kv swz 128B]

  const int tid = threadIdx.x;
  const int wv = tid >> 6, lane = tid & 63;
  const int q31 = lane & 31, hi = lane >> 5, l7 = lane & 7;
  const int kind = blockIdx.x >> 5, bh = blockIdx.x & 31;
  const int qt = KQT[kind], seg = KSEG[kind];
  const int nt = 2 * qt + 2;
  const int ns = qt >= 11 ? 3 : (qt >= 5 ? 2 : 1);
  const int t0 = (nt * seg) / ns, t1 = (nt * (seg + 1)) / ns;
  const bool split = ns > 1;

  const int q0 = qt * 128;
  const int qs = q0 + wv * 32;        // wave's q base
  const int qa = qs + q31;            // lane's absolute q row
  const size_t bhT = (size_t)bh * 2048;
  const bf16* Vh = Vt + (size_t)bh * 64 * 2048;

  bf16x8 qf[4];
#pragma unroll
  for (int kw = 0; kw < 4; ++kw)
    qf[kw] = *(const bf16x8*)(Q + (bhT + qa) * 64 + kw * 16 + hi * 8);

  u32x4 onesu; onesu[0] = onesu[1] = onesu[2] = onesu[3] = 0x3F803F80u;
  const bf16x8 ones8 = __builtin_bit_cast(bf16x8, onesu);

  f32x16 O0 = {}, O1 = {};   // O^T[d 0..31 / 32..63][q=q31]
  f32x16 Ol = {};            // row-sum accumulator (use [0])
  float m2 = NEG_BIG;        // running max in RAW S units

  auto STAGE_K = [&](int buf, int kv0) {
#pragma unroll
    for (int rr = 0; rr < 2; ++rr) {
      const int c = rr * 256 + tid;
      const int row = c >> 3, cc = c & 7;
      const int gcol = (cc ^ (row & 7)) * 8;
      gload_lds16(Ks[buf] + (rr * 256 + wv * 64) * 16,
                  Kk + (bhT + kv0 + row) * 64 + gcol);
    }
  };
  auto STAGE_V = [&](int buf, int kv0) {
#pragma unroll
    for (int rr = 0; rr < 2; ++rr) {
      const int c = rr * 256 + tid;
      const int row = c >> 3, cc = c & 7;
      const int gcol = (cc ^ (row & 7)) * 8;
      gload_lds16(Vs[buf] + (rr * 256 + wv * 64) * 16,
                  Vh + (size_t)row * 2048 + kv0 + gcol);
    }
  };

  // ---- prologue: V(t0), K(t0), K(t0+1); full drain once ----
  STAGE_V(t0 % 2, t0 * 64);
  STAGE_K(t0 % 3, t0 * 64);
  if (t0 + 1 < t1) STAGE_K((t0 + 1) % 3, (t0 + 1) * 64);
  asm volatile("s_waitcnt vmcnt(0)" ::: "memory");
  __builtin_amdgcn_s_barrier();
  __builtin_amdgcn_sched_barrier(0);

  for (int it = t0; it < t1; ++it) {
    const int kv0 = it * 64;
    // issue order matters: V(t+1) first, K(t+2) second (FIFO drain order)
    if (it + 1 < t1) STAGE_V((it + 1) % 2, (it + 1) * 64);
    if (it + 2 < t1) STAGE_K((it + 2) % 3, (it + 2) * 64);

    if (kv0 <= qs + 31) {   // wave-uniform: skip fully-masked tiles
      // ---- S^T = K . Q^T ----
      f32x16 S0 = {}, S1 = {};
      __builtin_amdgcn_s_setprio(1);
#pragma unroll
      for (int kw = 0; kw < 4; ++kw) {
        const int cb = (32 * kw + 16 * hi) ^ (l7 << 4);
        const bf16x8 k0 = *(const bf16x8*)(Ks[it % 3] + q31 * 128 + cb);
        const bf16x8 k1 = *(const bf16x8*)(Ks[it % 3] + (32 + q31) * 128 + cb);
        S0 = MFMA32(k0, qf[kw], S0);
        S1 = MFMA32(k1, qf[kw], S1);
      }
      __builtin_amdgcn_s_setprio(0);

      // ---- raw-domain P + causal mask ----
      float p[32];
#pragma unroll
      for (int r = 0; r < 16; ++r) { p[r] = S0[r]; p[16 + r] = S1[r]; }
      if (kv0 + 63 > qs) {
#pragma unroll
        for (int a = 0; a < 2; ++a)
#pragma unroll
          for (int r = 0; r < 16; ++r) {
            const int kva = kv0 + a * 32 + (r & 3) + 8 * (r >> 2) + 4 * hi;
            if (kva > qa) p[a * 16 + r] = NEG_BIG;
          }
      }

      // ---- running max (raw units) with defer (T13) ----
      float w16[16];
#pragma unroll
      for (int i = 0; i < 16; ++i) w16[i] = fmaxf(p[i], p[i + 16]);
#pragma unroll
      for (int i = 0; i < 8; ++i) w16[i] = fmaxf(w16[i], w16[i + 8]);
#pragma unroll
      for (int i = 0; i < 4; ++i) w16[i] = fmaxf(w16[i], w16[i + 4]);
      float mx = fmaxf(fmaxf(w16[0], w16[1]), fmaxf(w16[2], w16[3]));
      mx = fmaxf(mx, __shfl_xor(mx, 32));
      if (!__all(mx - m2 <= THR_RAW)) {
        const float mnew = fmaxf(m2, mx);
        const float fac = exp2f((m2 - mnew) * SCL_LOG2);  // 0 on first tile
#pragma unroll
        for (int r = 0; r < 16; ++r) { O0[r] *= fac; O1[r] *= fac; }
        Ol[0] *= fac;
        m2 = mnew;
      }
      const float nm2 = -m2 * SCL_LOG2;
#pragma unroll
      for (int i = 0; i < 32; ++i) p[i] = exp2f(__builtin_fmaf(p[i], SCL_LOG2, nm2));

      // ---- pack P rows -> B-operand frags (T12 pattern, static idx) ----
      bf16x8 pf[4];
#pragma unroll
      for (int ks = 0; ks < 4; ++ks) {
        const int base = 16 * (ks >> 1) + 8 * (ks & 1);
        const unsigned g0 = pk2(p[base + 0], p[base + 1]);
        const unsigned g1 = pk2(p[base + 2], p[base + 3]);
        const unsigned g2 = pk2(p[base + 4], p[base + 5]);
        const unsigned g3 = pk2(p[base + 6], p[base + 7]);
        const unsigned e0 = __shfl_xor(hi ? g0 : g2, 32);
        const unsigned e1 = __shfl_xor(hi ? g1 : g3, 32);
        u32x4 w4;
        w4[0] = hi ? e0 : g0;
        w4[1] = hi ? e1 : g1;
        w4[2] = hi ? g2 : e0;
        w4[3] = hi ? g3 : e1;
        pf[ks] = __builtin_bit_cast(bf16x8, w4);
      }

      // ---- O^T += V^T.P^T ; l += ones.P^T (matrix pipe) ----
      __builtin_amdgcn_s_setprio(1);
#pragma unroll
      for (int ks = 0; ks < 4; ++ks) {
        const int cb = (32 * ks + 16 * hi) ^ (l7 << 4);
        const bf16x8 v0 = *(const bf16x8*)(Vs[it % 2] + q31 * 128 + cb);
        const bf16x8 v1 = *(const bf16x8*)(Vs[it % 2] + (32 + q31) * 128 + cb);
        O0 = MFMA32(v0, pf[ks], O0);
        O1 = MFMA32(v1, pf[ks], O1);
        Ol = MFMA32(ones8, pf[ks], Ol);
      }
      __builtin_amdgcn_s_setprio(0);
    }

    // ---- tile boundary: counted wait, never 0 in steady state ----
    if (it + 1 < t1) {
      if (it + 2 < t1) {
        asm volatile("s_waitcnt vmcnt(2)" ::: "memory");  // K(t+2) stays in flight
      } else {
        asm volatile("s_waitcnt vmcnt(0)" ::: "memory");  // tail: only V(t+1) out
      }
      __builtin_amdgcn_s_barrier();
      __builtin_amdgcn_sched_barrier(0);
    }
  }

  const float l = Ol[0];
  if (!split) {
    const int b = bh >> 4, h = bh & 15;
    const float inv = 1.f / l;
    bf16* orow = attout + ((size_t)b * 2048 + qa) * 1024 + h * 64;
#pragma unroll
    for (int r = 0; r < 16; ++r) {
      const int dd = (r & 3) + 8 * (r >> 2) + 4 * hi;
      orow[dd]      = (bf16)(O0[r] * inv);
      orow[32 + dd] = (bf16)(O1[r] * inv);
    }
  } else {
    const int sbase = (qt < 11) ? (qt - 5) * 2 : 12 + (qt - 11) * 3;
    const int slot = bh * 27 + sbase + seg;
    bf16* Po = Opart + (size_t)slot * 8192;
    const int row = wv * 32 + q31;
#pragma unroll
    for (int r = 0; r < 16; ++r) {
      const int dd = (r & 3) + 8 * (r >> 2) + 4 * hi;
      Po[row * 64 + dd]      = (bf16)O0[r];
      Po[row * 64 + 32 + dd] = (bf16)O1[r];
    }
    Ml[slot * 256 + row]       = m2;
    Ml[slot * 256 + 128 + row] = l;
  }
}

// ---------------------------------------------------------------------------
// Combine: merge ns in {2,3} kv-segments of each (bh, qt>=5) into Aw.
// 352 blocks (32 bh x 11 qt) x 256 thr.
// ---------------------------------------------------------------------------
__global__ void attn_combine(const bf16* __restrict__ Opart,
                             const float* __restrict__ Ml,
                             bf16* __restrict__ attout) {
  const int u = blockIdx.x;
  const int bh = u / 11, qti = u - bh * 11;
  const int qt = qti + 5;
  const int ns = qt >= 11 ? 3 : 2;
  const int sbase = (qt < 11) ? (qt - 5) * 2 : 12 + (qt - 11) * 3;
  const int s0 = bh * 27 + sbase;
  const int tid = threadIdx.x;
  const int row = tid >> 1, c0 = (tid & 1) * 32;

  float m[3], lv[3];
  float M = NEG_BIG;
#pragma unroll
  for (int s = 0; s < 3; ++s)
    if (s < ns) {
      m[s] = Ml[(s0 + s) * 256 + row];
      lv[s] = Ml[(s0 + s) * 256 + 128 + row];
      M = fmaxf(M, m[s]);
    }
  float w[3], L = 0.f;
#pragma unroll
  for (int s = 0; s < 3; ++s)
    if (s < ns) {
      w[s] = exp2f((m[s] - M) * SCL_LOG2);
      L += w[s] * lv[s];
    }
  const float inv = 1.f / L;

  float acc[32] = {};
#pragma unroll
  for (int s = 0; s < 3; ++s)
    if (s < ns) {
      const bf16* p = Opart + (size_t)(s0 + s) * 8192 + row * 64 + c0;
      const float ws = w[s];
#pragma unroll
      for (int j = 0; j < 4; ++j) {
        const bf16x8 v = *(const bf16x8*)(p + j * 8);
#pragma unroll
        for (int e = 0; e < 8; ++e) acc[j * 8 + e] += ws * (float)v[e];
      }
    }

  const int b = bh >> 4, h = bh & 15, t = qt * 128 + row;
  bf16* dst = attout + ((size_t)b * 2048 + t) * 1024 + h * 64 + c0;
#pragma unroll
  for (int d = 0; d < 32; ++d) dst[d] = (bf16)(acc[d] * inv);
}

// ---------------------------------------------------------------------------
extern "C" void kernel_launch(void* const* d_in, const int* in_sizes, int n_in,
                              void* d_out, int out_size, void* d_ws, size_t ws_size,
                              hipStream_t stream) {
  const float* x   = (const float*)d_in[0];
  const float* xq  = (const float*)d_in[1];
  const float* Wq  = (const float*)d_in[2];
  const float* bq  = (const float*)d_in[3];
  const float* Wk  = (const float*)d_in[4];
  const float* bk  = (const float*)d_in[5];
  const float* Wv  = (const float*)d_in[6];
  const float* bv  = (const float*)d_in[7];
  const float* Wp  = (const float*)d_in[8];
  const float* bp  = (const float*)d_in[9];
  float* out = (float*)d_out;

  const size_t NTC = 4194304;  // B*T*C
  const size_t NW  = 1048576;  // C*C
  bf16* ws = (bf16*)d_ws;
  bf16* XQb = ws;
  bf16* Xb  = XQb + NTC;
  bf16* Wqb = Xb + NTC;
  bf16* Wkb = Wqb + NW;
  bf16* Wvb = Wkb + NW;
  bf16* Wpb = Wvb + NW;
  bf16* Qw  = Wpb + NW;              // [B*H, T, D]
  bf16* Kw  = Qw + NTC;
  bf16* Vtw = Kw + NTC;              // [B*H, D, T]
  bf16* Aw  = Vtw + NTC;             // [B, T, C]
  // Partials alias XQb/Xb (dead after gemm_qkv): 864 slots x 16KB = 13.5MB
  bf16* Opart = (bf16*)d_ws;
  float* Ml   = (float*)(Aw + NTC);  // 864 x 256 f32 = 0.88 MB

  dim3 blk(256);
  cvt6<<<dim3(6144), blk, 0, stream>>>(xq, x, Wq, Wk, Wv, Wp,
                                       XQb, Xb, Wqb, Wkb, Wvb, Wpb);
  gemm_qkv<<<dim3(24, 32), blk, 0, stream>>>(XQb, Xb, Wqb, Wkb, Wvb,
                                             bq, bk, bv, Qw, Kw, Vtw);
  attn_fwd<<<dim3(1024), blk, 0, stream>>>(Qw, Kw, Vtw, Aw, Opart, Ml);
  attn_combine<<<dim3(352), blk, 0, stream>>>(Opart, Ml, Aw);
  gemm_out<<<dim3(16, 32), blk, 0, stream>>>(Aw, Wpb, bp, out, 4096, 1024, 1024);
}

// Round 16
// 118.574 us; speedup vs baseline: 1.0202x; 1.0202x over previous
//
#include <hip/hip_runtime.h>

typedef __bf16 bf16;
typedef __attribute__((ext_vector_type(8))) __bf16 bf16x8;
typedef __attribute__((ext_vector_type(4))) float f32x4;
typedef __attribute__((ext_vector_type(16))) float f32x16;
typedef __attribute__((ext_vector_type(4))) unsigned u32x4;

#define MFMA16(a, b, c) __builtin_amdgcn_mfma_f32_16x16x32_bf16((a), (b), (c), 0, 0, 0)
#define MFMA32(a, b, c) __builtin_amdgcn_mfma_f32_32x32x16_bf16((a), (b), (c), 0, 0, 0)
#define NEG_BIG (-1e30f)
#define SCL_LOG2 0.18033688011112042f  /* log2(e)/sqrt(64) */
#define THR_RAW 44.3614195558365f      /* 8 / SCL_LOG2 */

__device__ __forceinline__ void gload_lds16(void* lds, const void* g) {
  __builtin_amdgcn_global_load_lds(
      (const __attribute__((address_space(1))) void*)g,
      (__attribute__((address_space(3))) void*)lds, 16, 0, 0);
}

__device__ __forceinline__ unsigned pk2(float x, float y) {
  const unsigned short a = __builtin_bit_cast(unsigned short, (bf16)x);
  const unsigned short b = __builtin_bit_cast(unsigned short, (bf16)y);
  return (unsigned)a | ((unsigned)b << 16);
}

// Round-10 LPT schedule (measured best): kind -> (qt, seg).
// ns(qt): qt>=11 -> 3, 5..10 -> 2, else 1. Max chain = 11 tiles.
static __device__ const signed char KQT[32] =
  {15,15,10,10, 15,14,14,14,13, 9, 9, 4, 13,13,12,12, 8, 8,
   12,11,11,11, 7, 7, 3,  6, 6,  5, 5, 2,  1,  0};
static __device__ const signed char KSEG[32] =
  { 0, 1, 0, 1,  2, 0, 1, 2, 0, 0, 1, 0,  1, 2, 0, 1, 0, 1,
    2, 0, 1, 2, 0, 1, 0,  0, 1,  0, 1, 0,  0,  0};

// ---------------------------------------------------------------------------
// Fused f32 -> bf16 conversion for all 6 tensors (1 launch).
// ---------------------------------------------------------------------------
__global__ void cvt6(const float* __restrict__ s0, const float* __restrict__ s1,
                     const float* __restrict__ s2, const float* __restrict__ s3,
                     const float* __restrict__ s4, const float* __restrict__ s5,
                     bf16* __restrict__ d0, bf16* __restrict__ d1,
                     bf16* __restrict__ d2, bf16* __restrict__ d3,
                     bf16* __restrict__ d4, bf16* __restrict__ d5) {
  const int c = blockIdx.x * blockDim.x + threadIdx.x;
  if (c >= 1572864) return;
  const float* s; bf16* d; int off;
  if (c < 524288)        { s = s0; d = d0; off = c; }
  else if (c < 1048576)  { s = s1; d = d1; off = c - 524288; }
  else {
    const int c2 = c - 1048576, seg = c2 >> 17;
    off = c2 & 131071;
    s = seg == 0 ? s2 : seg == 1 ? s3 : seg == 2 ? s4 : s5;
    d = seg == 0 ? d2 : seg == 1 ? d3 : seg == 2 ? d4 : d5;
  }
  const float4 a = ((const float4*)s)[off * 2 + 0];
  const float4 b = ((const float4*)s)[off * 2 + 1];
  bf16x8 o;
  o[0] = (bf16)a.x; o[1] = (bf16)a.y; o[2] = (bf16)a.z; o[3] = (bf16)a.w;
  o[4] = (bf16)b.x; o[5] = (bf16)b.y; o[6] = (bf16)b.z; o[7] = (bf16)b.w;
  ((bf16x8*)d)[off] = o;
}

// ---------------------------------------------------------------------------
// Merged Q+K+V projection, BK=64 (round-12 verified): 768 blocks (3/CU).
// ---------------------------------------------------------------------------
__global__ void gemm_qkv(const bf16* __restrict__ XQ, const bf16* __restrict__ X,
                         const bf16* __restrict__ Wq, const bf16* __restrict__ Wk,
                         const bf16* __restrict__ Wv,
                         const float* __restrict__ bq, const float* __restrict__ bk,
                         const float* __restrict__ bv,
                         bf16* __restrict__ Qo, bf16* __restrict__ Ko,
                         bf16* __restrict__ Vto) {
  __shared__ __align__(16) char As[128 * 128];   // [row][64 elems swz]
  __shared__ __align__(16) char Bs[128 * 128];
  const int tid = threadIdx.x;
  const int wv = tid >> 6, lane = tid & 63;
  const int wr = wv >> 1, wc = wv & 1;
  const int lr = lane & 15, lg = lane >> 4;
  const int seg = blockIdx.x >> 3;
  const int n0 = (blockIdx.x & 7) * 128;
  const int m0 = blockIdx.y * 128;
  const bf16* __restrict__ A = seg == 0 ? XQ : X;
  const bf16* __restrict__ W = seg == 0 ? Wq : seg == 1 ? Wk : Wv;
  const float* __restrict__ bias = seg == 0 ? bq : seg == 1 ? bk : bv;
  const int K = 1024;

  f32x4 acc[4][4] = {};

  for (int k0 = 0; k0 < K; k0 += 64) {
    __syncthreads();
#pragma unroll
    for (int j = 0; j < 4; ++j) {
      const int c = j * 256 + tid;
      const int row = c >> 3, cc = c & 7;
      const int gcol = (cc ^ (row & 7)) * 8;
      gload_lds16(As + (j * 256 + wv * 64) * 16,
                  A + (size_t)(m0 + row) * K + k0 + gcol);
      gload_lds16(Bs + (j * 256 + wv * 64) * 16,
                  W + (size_t)(n0 + row) * K + k0 + gcol);
    }
    __syncthreads();
#pragma unroll
    for (int half = 0; half < 2; ++half) {
      const int kb = half * 64 + lg * 16;
      bf16x8 af[4], bfr[4];
#pragma unroll
      for (int i = 0; i < 4; ++i) {
        const int row = wr * 64 + i * 16 + lr;
        af[i] = *(const bf16x8*)(As + row * 128 + (kb ^ ((row & 7) << 4)));
      }
#pragma unroll
      for (int j = 0; j < 4; ++j) {
        const int row = wc * 64 + j * 16 + lr;
        bfr[j] = *(const bf16x8*)(Bs + row * 128 + (kb ^ ((row & 7) << 4)));
      }
#pragma unroll
      for (int i = 0; i < 4; ++i)
#pragma unroll
        for (int j = 0; j < 4; ++j)
          acc[i][j] = MFMA16(af[i], bfr[j], acc[i][j]);
    }
  }

#pragma unroll
  for (int j = 0; j < 4; ++j) {
    const int n = n0 + wc * 64 + j * 16 + lr;
    const float bvv = bias[n];
    const int h = n >> 6, d = n & 63;
#pragma unroll
    for (int i = 0; i < 4; ++i) {
#pragma unroll
      for (int r = 0; r < 4; ++r) {
        const int m = m0 + wr * 64 + i * 16 + lg * 4 + r;
        const float v = acc[i][j][r] + bvv;
        const int b = m >> 11, t = m & 2047;
        if (seg == 0)      Qo[((size_t)(b * 16 + h) * 2048 + t) * 64 + d] = (bf16)v;
        else if (seg == 1) Ko[((size_t)(b * 16 + h) * 2048 + t) * 64 + d] = (bf16)v;
        else               Vto[((size_t)(b * 16 + h) * 64 + d) * 2048 + t] = (bf16)v;
      }
    }
  }
}

// ---------------------------------------------------------------------------
// Final projection GEMM, BK=64, BN=64 (round-12 verified): 512 blocks.
// ---------------------------------------------------------------------------
__global__ void gemm_out(const bf16* __restrict__ A, const bf16* __restrict__ W,
                         const float* __restrict__ bias, float* __restrict__ out,
                         int M, int N, int K) {
  __shared__ __align__(16) char As[128 * 128];  // [row][64 elems swz]
  __shared__ __align__(16) char Bs[64 * 128];
  const int tid = threadIdx.x;
  const int wv = tid >> 6, lane = tid & 63;
  const int wr = wv >> 1, wc = wv & 1;
  const int lr = lane & 15, lg = lane >> 4;
  const int m0 = blockIdx.y * 128, n0 = blockIdx.x * 64;

  f32x4 acc[4][2] = {};

  for (int k0 = 0; k0 < K; k0 += 64) {
    __syncthreads();
#pragma unroll
    for (int j = 0; j < 4; ++j) {
      const int c = j * 256 + tid;
      const int row = c >> 3, cc = c & 7;
      const int gcol = (cc ^ (row & 7)) * 8;
      gload_lds16(As + (j * 256 + wv * 64) * 16,
                  A + (size_t)(m0 + row) * K + k0 + gcol);
    }
#pragma unroll
    for (int j = 0; j < 2; ++j) {
      const int c = j * 256 + tid;
      const int row = c >> 3, cc = c & 7;
      const int gcol = (cc ^ (row & 7)) * 8;
      gload_lds16(Bs + (j * 256 + wv * 64) * 16,
                  W + (size_t)(n0 + row) * K + k0 + gcol);
    }
    __syncthreads();
#pragma unroll
    for (int half = 0; half < 2; ++half) {
      const int kb = half * 64 + lg * 16;
      bf16x8 af[4], bfr[2];
#pragma unroll
      for (int i = 0; i < 4; ++i) {
        const int row = wr * 64 + i * 16 + lr;
        af[i] = *(const bf16x8*)(As + row * 128 + (kb ^ ((row & 7) << 4)));
      }
#pragma unroll
      for (int j = 0; j < 2; ++j) {
        const int row = wc * 32 + j * 16 + lr;
        bfr[j] = *(const bf16x8*)(Bs + row * 128 + (kb ^ ((row & 7) << 4)));
      }
#pragma unroll
      for (int i = 0; i < 4; ++i)
#pragma unroll
        for (int j = 0; j < 2; ++j)
          acc[i][j] = MFMA16(af[i], bfr[j], acc[i][j]);
    }
  }

#pragma unroll
  for (int j = 0; j < 2; ++j) {
    const int n = n0 + wc * 32 + j * 16 + lr;
    const float bv = bias[n];
#pragma unroll
    for (int i = 0; i < 4; ++i) {
#pragma unroll
      for (int r = 0; r < 4; ++r) {
        const int m = m0 + wr * 64 + i * 16 + lg * 4 + r;
        out[(size_t)m * N + n] = acc[i][j][r] + bv;
      }
    }
  }
}

// ---------------------------------------------------------------------------
// Causal flash attention — round-10 structure (measured best), unchanged.
// 1024 blocks: kind = bid>>5 -> (qt, seg); bh = bid&31.
// ---------------------------------------------------------------------------
__global__ void attn_fwd(const bf16* __restrict__ Q, const bf16* __restrict__ Kk,
                         const bf16* __restrict__ Vt, bf16* __restrict__ attout,
                         bf16* __restrict__ Opart, float* __restrict__ Ml) {
  __shared__ __align__(16) char Ks[2][8192];   // [kv 64][d swz 128B]
  __shared__ __align__(16) char Vs[2][8192];   // [d 64][kv swz 128B]

  const int tid = threadIdx.x;
  const int wv = tid >> 6, lane = tid & 63;
  const int q31 = lane & 31, hi = lane >> 5, l7 = lane & 7;
  const int kind = blockIdx.x >> 5, bh = blockIdx.x & 31;
  const int qt = KQT[kind], seg = KSEG[kind];
  const int nt = 2 * qt + 2;
  const int ns = qt >= 11 ? 3 : (qt >= 5 ? 2 : 1);
  const int t0 = (nt * seg) / ns, t1 = (nt * (seg + 1)) / ns;
  const bool split = ns > 1;

  const int q0 = qt * 128;
  const int qs = q0 + wv * 32;        // wave's q base
  const int qa = qs + q31;            // lane's absolute q row
  const size_t bhT = (size_t)bh * 2048;
  const bf16* Vh = Vt + (size_t)bh * 64 * 2048;

  bf16x8 qf[4];
#pragma unroll
  for (int kw = 0; kw < 4; ++kw)
    qf[kw] = *(const bf16x8*)(Q + (bhT + qa) * 64 + kw * 16 + hi * 8);

  u32x4 onesu; onesu[0] = onesu[1] = onesu[2] = onesu[3] = 0x3F803F80u;
  const bf16x8 ones8 = __builtin_bit_cast(bf16x8, onesu);

  f32x16 O0 = {}, O1 = {};   // O^T[d 0..31 / 32..63][q=q31]
  f32x16 Ol = {};            // row-sum accumulator (use [0])
  float m2 = NEG_BIG;        // running max in RAW S units

  auto STAGE = [&](int buf, int kv0) {
#pragma unroll
    for (int rr = 0; rr < 2; ++rr) {
      const int c = rr * 256 + tid;
      const int row = c >> 3, cc = c & 7;
      const int gcol = (cc ^ (row & 7)) * 8;
      gload_lds16(Ks[buf] + (rr * 256 + wv * 64) * 16,
                  Kk + (bhT + kv0 + row) * 64 + gcol);
      gload_lds16(Vs[buf] + (rr * 256 + wv * 64) * 16,
                  Vh + (size_t)row * 2048 + kv0 + gcol);
    }
  };

  STAGE(0, t0 * 64);
  __syncthreads();

  for (int it = t0; it < t1; ++it) {
    const int kv0 = it * 64;
    const int cur = (it - t0) & 1;
    if (it + 1 < t1) STAGE(cur ^ 1, (it + 1) * 64);

    if (kv0 <= qs + 31) {   // wave-uniform: skip fully-masked tiles
      // ---- S^T = K . Q^T ----
      f32x16 S0 = {}, S1 = {};
      __builtin_amdgcn_s_setprio(1);
#pragma unroll
      for (int kw = 0; kw < 4; ++kw) {
        const int cb = (32 * kw + 16 * hi) ^ (l7 << 4);
        const bf16x8 k0 = *(const bf16x8*)(Ks[cur] + q31 * 128 + cb);
        const bf16x8 k1 = *(const bf16x8*)(Ks[cur] + (32 + q31) * 128 + cb);
        S0 = MFMA32(k0, qf[kw], S0);
        S1 = MFMA32(k1, qf[kw], S1);
      }
      __builtin_amdgcn_s_setprio(0);

      // ---- raw-domain P + causal mask ----
      float p[32];
#pragma unroll
      for (int r = 0; r < 16; ++r) { p[r] = S0[r]; p[16 + r] = S1[r]; }
      if (kv0 + 63 > qs) {
#pragma unroll
        for (int a = 0; a < 2; ++a)
#pragma unroll
          for (int r = 0; r < 16; ++r) {
            const int kva = kv0 + a * 32 + (r & 3) + 8 * (r >> 2) + 4 * hi;
            if (kva > qa) p[a * 16 + r] = NEG_BIG;
          }
      }

      // ---- running max (raw units) with defer (T13) ----
      float w16[16];
#pragma unroll
      for (int i = 0; i < 16; ++i) w16[i] = fmaxf(p[i], p[i + 16]);
#pragma unroll
      for (int i = 0; i < 8; ++i) w16[i] = fmaxf(w16[i], w16[i + 8]);
#pragma unroll
      for (int i = 0; i < 4; ++i) w16[i] = fmaxf(w16[i], w16[i + 4]);
      float mx = fmaxf(fmaxf(w16[0], w16[1]), fmaxf(w16[2], w16[3]));
      mx = fmaxf(mx, __shfl_xor(mx, 32));
      if (!__all(mx - m2 <= THR_RAW)) {
        const float mnew = fmaxf(m2, mx);
        const float fac = exp2f((m2 - mnew) * SCL_LOG2);  // 0 on first tile
#pragma unroll
        for (int r = 0; r < 16; ++r) { O0[r] *= fac; O1[r] *= fac; }
        Ol[0] *= fac;
        m2 = mnew;
      }
      const float nm2 = -m2 * SCL_LOG2;
#pragma unroll
      for (int i = 0; i < 32; ++i) p[i] = exp2f(__builtin_fmaf(p[i], SCL_LOG2, nm2));

      // ---- pack P rows -> B-operand frags (T12 pattern, static idx) ----
      bf16x8 pf[4];
#pragma unroll
      for (int ks = 0; ks < 4; ++ks) {
        const int base = 16 * (ks >> 1) + 8 * (ks & 1);
        const unsigned g0 = pk2(p[base + 0], p[base + 1]);
        const unsigned g1 = pk2(p[base + 2], p[base + 3]);
        const unsigned g2 = pk2(p[base + 4], p[base + 5]);
        const unsigned g3 = pk2(p[base + 6], p[base + 7]);
        const unsigned e0 = __shfl_xor(hi ? g0 : g2, 32);
        const unsigned e1 = __shfl_xor(hi ? g1 : g3, 32);
        u32x4 w4;
        w4[0] = hi ? e0 : g0;
        w4[1] = hi ? e1 : g1;
        w4[2] = hi ? g2 : e0;
        w4[3] = hi ? g3 : e1;
        pf[ks] = __builtin_bit_cast(bf16x8, w4);
      }

      // ---- O^T += V^T.P^T ; l += ones.P^T (matrix pipe) ----
      __builtin_amdgcn_s_setprio(1);
#pragma unroll
      for (int ks = 0; ks < 4; ++ks) {
        const int cb = (32 * ks + 16 * hi) ^ (l7 << 4);
        const bf16x8 v0 = *(const bf16x8*)(Vs[cur] + q31 * 128 + cb);
        const bf16x8 v1 = *(const bf16x8*)(Vs[cur] + (32 + q31) * 128 + cb);
        O0 = MFMA32(v0, pf[ks], O0);
        O1 = MFMA32(v1, pf[ks], O1);
        Ol = MFMA32(ones8, pf[ks], Ol);
      }
      __builtin_amdgcn_s_setprio(0);
    }
    __syncthreads();
  }

  const float l = Ol[0];
  if (!split) {
    const int b = bh >> 4, h = bh & 15;
    const float inv = 1.f / l;
    bf16* orow = attout + ((size_t)b * 2048 + qa) * 1024 + h * 64;
#pragma unroll
    for (int r = 0; r < 16; ++r) {
      const int dd = (r & 3) + 8 * (r >> 2) + 4 * hi;
      orow[dd]      = (bf16)(O0[r] * inv);
      orow[32 + dd] = (bf16)(O1[r] * inv);
    }
  } else {
    const int sbase = (qt < 11) ? (qt - 5) * 2 : 12 + (qt - 11) * 3;
    const int slot = bh * 27 + sbase + seg;
    bf16* Po = Opart + (size_t)slot * 8192;
    const int row = wv * 32 + q31;
#pragma unroll
    for (int r = 0; r < 16; ++r) {
      const int dd = (r & 3) + 8 * (r >> 2) + 4 * hi;
      Po[row * 64 + dd]      = (bf16)O0[r];
      Po[row * 64 + 32 + dd] = (bf16)O1[r];
    }
    Ml[slot * 256 + row]       = m2;
    Ml[slot * 256 + 128 + row] = l;
  }
}

// ---------------------------------------------------------------------------
// Combine: merge ns in {2,3} kv-segments of each (bh, qt>=5) into Aw.
// 352 blocks (32 bh x 11 qt) x 256 thr.
// ---------------------------------------------------------------------------
__global__ void attn_combine(const bf16* __restrict__ Opart,
                             const float* __restrict__ Ml,
                             bf16* __restrict__ attout) {
  const int u = blockIdx.x;
  const int bh = u / 11, qti = u - bh * 11;
  const int qt = qti + 5;
  const int ns = qt >= 11 ? 3 : 2;
  const int sbase = (qt < 11) ? (qt - 5) * 2 : 12 + (qt - 11) * 3;
  const int s0 = bh * 27 + sbase;
  const int tid = threadIdx.x;
  const int row = tid >> 1, c0 = (tid & 1) * 32;

  float m[3], lv[3];
  float M = NEG_BIG;
#pragma unroll
  for (int s = 0; s < 3; ++s)
    if (s < ns) {
      m[s] = Ml[(s0 + s) * 256 + row];
      lv[s] = Ml[(s0 + s) * 256 + 128 + row];
      M = fmaxf(M, m[s]);
    }
  float w[3], L = 0.f;
#pragma unroll
  for (int s = 0; s < 3; ++s)
    if (s < ns) {
      w[s] = exp2f((m[s] - M) * SCL_LOG2);
      L += w[s] * lv[s];
    }
  const float inv = 1.f / L;

  float acc[32] = {};
#pragma unroll
  for (int s = 0; s < 3; ++s)
    if (s < ns) {
      const bf16* p = Opart + (size_t)(s0 + s) * 8192 + row * 64 + c0;
      const float ws = w[s];
#pragma unroll
      for (int j = 0; j < 4; ++j) {
        const bf16x8 v = *(const bf16x8*)(p + j * 8);
#pragma unroll
        for (int e = 0; e < 8; ++e) acc[j * 8 + e] += ws * (float)v[e];
      }
    }

  const int b = bh >> 4, h = bh & 15, t = qt * 128 + row;
  bf16* dst = attout + ((size_t)b * 2048 + t) * 1024 + h * 64 + c0;
#pragma unroll
  for (int d = 0; d < 32; ++d) dst[d] = (bf16)(acc[d] * inv);
}

// ---------------------------------------------------------------------------
extern "C" void kernel_launch(void* const* d_in, const int* in_sizes, int n_in,
                              void* d_out, int out_size, void* d_ws, size_t ws_size,
                              hipStream_t stream) {
  const float* x   = (const float*)d_in[0];
  const float* xq  = (const float*)d_in[1];
  const float* Wq  = (const float*)d_in[2];
  const float* bq  = (const float*)d_in[3];
  const float* Wk  = (const float*)d_in[4];
  const float* bk  = (const float*)d_in[5];
  const float* Wv  = (const float*)d_in[6];
  const float* bv  = (const float*)d_in[7];
  const float* Wp  = (const float*)d_in[8];
  const float* bp  = (const float*)d_in[9];
  float* out = (float*)d_out;

  const size_t NTC = 4194304;  // B*T*C
  const size_t NW  = 1048576;  // C*C
  bf16* ws = (bf16*)d_ws;
  bf16* XQb = ws;
  bf16* Xb  = XQb + NTC;
  bf16* Wqb = Xb + NTC;
  bf16* Wkb = Wqb + NW;
  bf16* Wvb = Wkb + NW;
  bf16* Wpb = Wvb + NW;
  bf16* Qw  = Wpb + NW;              // [B*H, T, D]
  bf16* Kw  = Qw + NTC;
  bf16* Vtw = Kw + NTC;              // [B*H, D, T]
  bf16* Aw  = Vtw + NTC;             // [B, T, C]
  // Partials alias XQb/Xb (dead after gemm_qkv): 864 slots x 16KB = 13.5MB
  bf16* Opart = (bf16*)d_ws;
  float* Ml   = (float*)(Aw + NTC);  // 864 x 256 f32 = 0.88 MB

  dim3 blk(256);
  cvt6<<<dim3(6144), blk, 0, stream>>>(xq, x, Wq, Wk, Wv, Wp,
                                       XQb, Xb, Wqb, Wkb, Wvb, Wpb);
  gemm_qkv<<<dim3(24, 32), blk, 0, stream>>>(XQb, Xb, Wqb, Wkb, Wvb,
                                             bq, bk, bv, Qw, Kw, Vtw);
  attn_fwd<<<dim3(1024), blk, 0, stream>>>(Qw, Kw, Vtw, Aw, Opart, Ml);
  attn_combine<<<dim3(352), blk, 0, stream>>>(Opart, Ml, Aw);
  gemm_out<<<dim3(16, 32), blk, 0, stream>>>(Aw, Wpb, bp, out, 4096, 1024, 1024);
}